// Round 18
// baseline (77.054 us; speedup 1.0000x reference)
//
#include <hip/hip_runtime.h>

namespace {

typedef short bf16x8 __attribute__((ext_vector_type(8)));
typedef float f32x4 __attribute__((ext_vector_type(4)));

constexpr int BATCH = 8192;
constexpr int NMOD  = 64;
constexpr int CAP   = 256;   // Bin(8192,1/64) max ~170 << 256 (validated r1-r17)
constexpr int CSTR  = 16;    // counter stride in ints = 64B
constexpr float WB  = 1.0f / (7.0f * 0.5f);  // 2/7

// ws layout (float offsets) — r9/r14 layout
constexpr size_t OFF_WHI = 0;        // ushort[64*128*128] Wm hi [m][o][i]
constexpr size_t OFF_WLO = 524288;   // lo
constexpr size_t OFF_XH0 = 1048576;  // ushort[8192*128] X hi (hop0/2 out)
constexpr size_t OFF_XL0 = 1572864;  // lo
constexpr size_t OFF_XH1 = 2097152;  // ushort[8192*128] X hi (hop1 out)
constexpr size_t OFF_XL1 = 2621440;  // lo
constexpr size_t OFF_W1H = 3145728;  // ushort[512*128] W1 hi [col][k]
constexpr size_t OFF_W1L = 3178496;
constexpr size_t OFF_W2H = 3211264;  // ushort[64*512]  W2 hi [o][k]
constexpr size_t OFF_W2L = 3227648;
constexpr size_t OFF_CNT = 3244032;  // 192*CSTR ints (written by ballot blocks)
constexpr size_t OFF_BKT = 3247104;  // 3*64*CAP ints

__device__ __forceinline__ ushort f2bf(float x) {  // RTN-even f32->bf16 bits
  unsigned u = __builtin_bit_cast(unsigned, x);
  u += 0x7FFFu + ((u >> 16) & 1u);
  return (ushort)(u >> 16);
}
__device__ __forceinline__ float bf2f(ushort h) {
  return __builtin_bit_cast(float, ((unsigned)h) << 16);
}
__device__ __forceinline__ void cvt8(const float* v, bf16x8& hi, bf16x8& lo) {
#pragma unroll
  for (int j = 0; j < 8; ++j) {
    const float x = v[j];
    const ushort h = f2bf(x);
    hi[j] = (short)h;
    lo[j] = (short)f2bf(x - bf2f(h));
  }
}

// ---- prep: hi/lo conversions + ballot-scan buckets (no memset needed) -----
// bx 0..511: Wm; 512..543: W1; 544..559: W2; 560..751: ballot bucket (h,m)
__global__ __launch_bounds__(256) void k_prep(const float* __restrict__ Wm,
                                              const float* __restrict__ W1,
                                              const float* __restrict__ W2,
                                              const int* __restrict__ mids,
                                              float* __restrict__ ws) {
  __shared__ int wsum[4];
  const int bx = blockIdx.x;
  const int tid = threadIdx.x;
  if (bx < 560) {  // elementwise f32 -> bf16 hi/lo, layout preserved
    const float* src;
    ushort *dh, *dl;
    size_t i8;
    if (bx < 512) {
      src = Wm; dh = (ushort*)(ws + OFF_WHI); dl = (ushort*)(ws + OFF_WLO);
      i8 = (size_t)bx * 256 + tid;
    } else if (bx < 544) {
      src = W1; dh = (ushort*)(ws + OFF_W1H); dl = (ushort*)(ws + OFF_W1L);
      i8 = (size_t)(bx - 512) * 256 + tid;
    } else {
      src = W2; dh = (ushort*)(ws + OFF_W2H); dl = (ushort*)(ws + OFF_W2L);
      i8 = (size_t)(bx - 544) * 256 + tid;
    }
    float v[8];
    *(float4*)&v[0] = *(const float4*)&src[i8 * 8];
    *(float4*)&v[4] = *(const float4*)&src[i8 * 8 + 4];
    bf16x8 hi, lo;
    cvt8(v, hi, lo);
    *(bf16x8*)&dh[i8 * 8] = hi;
    *(bf16x8*)&dl[i8 * 8] = lo;
  } else {  // ballot bucket (h,m): scan mids[:,h], compact sorted by b
    const int hm = bx - 560;
    const int h = hm / NMOD, m = hm & 63;
    int* cnt = (int*)(ws + OFF_CNT);
    int* bkt = (int*)(ws + OFF_BKT) + hm * CAP;
    const int wv = tid >> 6, ln = tid & 63;
    int count = 0;
    for (int it = 0; it < BATCH / 256; ++it) {
      const int b = it * 256 + tid;
      const bool hit = (mids[b * 3 + h] == m);
      const unsigned long long mask = __ballot(hit);
      const int pre = __popcll(mask & ((1ull << ln) - 1ull));
      if (ln == 0) wsum[wv] = __popcll(mask);
      __syncthreads();
      int wbase = count;
#pragma unroll
      for (int u = 0; u < 4; ++u)
        if (u < wv) wbase += wsum[u];
      if (hit) bkt[wbase + pre] = b;
      count += wsum[0] + wsum[1] + wsum[2] + wsum[3];
      __syncthreads();
    }
    if (tid == 0) cnt[hm * CSTR] = count;
  }
}

// ---- hop (r17-proven): 512-thread blocks, 8 waves share one staged tile ---
template <int HOP>
__global__ __launch_bounds__(512, 1) void k_hop(const float* __restrict__ E,
                                                const int* __restrict__ eids,
                                                float* __restrict__ ws) {
  const int m = blockIdx.x >> 2, sl = blockIdx.x & 3;
  const int cn = ((const int*)(ws + OFF_CNT))[(HOP * NMOD + m) * CSTR];
  const int r0 = sl * 64;
  if (r0 >= cn) return;
  const int nr = min(64, cn - r0);

  __shared__ ushort wh[128 * 72];  // 18 KB
  __shared__ ushort wl[128 * 72];  // 18 KB
  __shared__ int rows[64], esrc[64], ebia[64];

  const int tid = threadIdx.x;
  const ushort* WhiG = (const ushort*)(ws + OFF_WHI) + (size_t)m * 16384;
  const ushort* WloG = (const ushort*)(ws + OFF_WLO) + (size_t)m * 16384;
  const int* bkt = (const int*)(ws + OFF_BKT) + (HOP * NMOD + m) * CAP + r0;
  const ushort* XHp = (const ushort*)(ws + (HOP == 2 ? OFF_XH1 : OFF_XH0));
  const ushort* XLp = (const ushort*)(ws + (HOP == 2 ? OFF_XL1 : OFF_XL0));
  ushort* XHn = (ushort*)(ws + (HOP == 1 ? OFF_XH1 : OFF_XH0));
  ushort* XLn = (ushort*)(ws + (HOP == 1 ? OFF_XL1 : OFF_XL0));

  if (tid < 64) {
    const int b = bkt[tid < nr ? tid : 0];
    rows[tid] = b;
    esrc[tid] = (HOP == 0) ? eids[b * 4] : b;
    ebia[tid] = eids[b * 4 + HOP + 1];
  }

  const int w = tid >> 6, l = tid & 63;
  const int lg = l >> 4, lr = l & 15;
  const int g = w & 3;            // rowgroup (16 rows)
  const int f0 = (w >> 2) * 4;    // first of 4 colfrags

  f32x4 acc[4] = {};

#pragma unroll
  for (int p = 0; p < 2; ++p) {
    __syncthreads();  // rows ready (p=0) / prev phase reads done (p=1)
    for (int e = tid; e < 128 * 8; e += 512) {
      const int c = e >> 3, s = e & 7;
      *(bf16x8*)&wh[c * 72 + s * 8] =
          *(const bf16x8*)&WhiG[(size_t)c * 128 + p * 64 + s * 8];
      *(bf16x8*)&wl[c * 72 + s * 8] =
          *(const bf16x8*)&WloG[(size_t)c * 128 + p * 64 + s * 8];
    }
    __syncthreads();

    bf16x8 ah[2], al[2];
    {
      const int row = g * 16 + lr;
#pragma unroll
      for (int s = 0; s < 2; ++s) {
        const int k0 = p * 64 + s * 32 + lg * 8;
        if (HOP == 0) {
          const float* sp = E + (size_t)esrc[row] * 128;
          float v[8];
          *(float4*)&v[0] = *(const float4*)&sp[k0];
          *(float4*)&v[4] = *(const float4*)&sp[k0 + 4];
          cvt8(v, ah[s], al[s]);
        } else {
          const size_t xo = (size_t)esrc[row] * 128 + k0;
          ah[s] = *(const bf16x8*)&XHp[xo];
          al[s] = *(const bf16x8*)&XLp[xo];
        }
      }
    }

#pragma unroll
    for (int f = 0; f < 4; ++f) {
      const int c = (f0 + f) * 16 + lr;
#pragma unroll
      for (int s = 0; s < 2; ++s) {
        const bf16x8 bh = *(const bf16x8*)&wh[c * 72 + s * 32 + lg * 8];
        const bf16x8 bl = *(const bf16x8*)&wl[c * 72 + s * 32 + lg * 8];
        acc[f] = __builtin_amdgcn_mfma_f32_16x16x32_bf16(ah[s], bh, acc[f], 0, 0, 0);
        acc[f] = __builtin_amdgcn_mfma_f32_16x16x32_bf16(al[s], bh, acc[f], 0, 0, 0);
        acc[f] = __builtin_amdgcn_mfma_f32_16x16x32_bf16(ah[s], bl, acc[f], 0, 0, 0);
      }
    }
  }

  // epilogue: C/D col=lane&15, row=4*(lane>>4)+q (validated r8/r9)
#pragma unroll
  for (int q = 0; q < 4; ++q) {
    const int row = g * 16 + lg * 4 + q;
    if (row < nr) {
      const int b = rows[row];
      const float* bp = E + (size_t)ebia[row] * 128;
      const size_t ob = (size_t)b * 128;
#pragma unroll
      for (int f = 0; f < 4; ++f) {
        const int col = (f0 + f) * 16 + lr;
        const float bias = bp[col];
        float v = fmaxf(acc[f][q] + bias, 0.f);
        if (HOP == 2) v = (1.f - WB) * bias + WB * v;
        const ushort h = f2bf(v);
        XHn[ob + col] = h;
        XLn[ob + col] = f2bf(v - bf2f(h));
      }
    }
  }
}

// ---- fused MLP: 512-thread, 32-row blocks (grid 256) ----------------------
// phase A: wave w = (rowgroup w&1 of 2, col-quarter w>>1 of 4 x 128 cols);
//   A = X frags (global), B = W1 [col][k] direct from L2 (staging proven
//   neutral r14). H -> bf16 hi/lo LDS [32][520].
// phase B: wave w = (o-block w&3, row-half w>>2); A = W2 [o][k], B = H^T.
constexpr int HSTR = 520;
__global__ __launch_bounds__(512, 2) void k_mlp(const float* __restrict__ b1,
                                                const float* __restrict__ b2,
                                                float* __restrict__ ws,
                                                float* __restrict__ out) {
  __shared__ ushort hh[32 * HSTR];  // 33280 B
  __shared__ ushort hl[32 * HSTR];  // 33280 B (total 66560 -> 2 blocks/CU)
  const int tid = threadIdx.x;
  const int row0 = blockIdx.x * 32;
  const ushort* XH = (const ushort*)(ws + OFF_XH0);
  const ushort* XL = (const ushort*)(ws + OFF_XL0);
  const ushort* W1H = (const ushort*)(ws + OFF_W1H);
  const ushort* W1L = (const ushort*)(ws + OFF_W1L);
  const ushort* W2H = (const ushort*)(ws + OFF_W2H);
  const ushort* W2L = (const ushort*)(ws + OFF_W2L);

  const int w = tid >> 6, l = tid & 63;
  const int lg = l >> 4, lr = l & 15;

  // phase A: wave w handles rows rowg*16..+15, cols colq*128..+127
  const int rowg = w & 1, colq = w >> 1;
  bf16x8 ah[4], al[4];
#pragma unroll
  for (int s = 0; s < 4; ++s) {
    const size_t xo = (size_t)(row0 + rowg * 16 + lr) * 128 + s * 32 + lg * 8;
    ah[s] = *(const bf16x8*)&XH[xo];
    al[s] = *(const bf16x8*)&XL[xo];
  }
  f32x4 acc[8] = {};
#pragma unroll
  for (int f = 0; f < 8; ++f) {
    const int c = colq * 128 + f * 16 + lr;
#pragma unroll
    for (int s = 0; s < 4; ++s) {
      const size_t wo = (size_t)c * 128 + s * 32 + lg * 8;
      const bf16x8 bh = *(const bf16x8*)&W1H[wo];
      const bf16x8 bl = *(const bf16x8*)&W1L[wo];
      acc[f] = __builtin_amdgcn_mfma_f32_16x16x32_bf16(ah[s], bh, acc[f], 0, 0, 0);
      acc[f] = __builtin_amdgcn_mfma_f32_16x16x32_bf16(al[s], bh, acc[f], 0, 0, 0);
      acc[f] = __builtin_amdgcn_mfma_f32_16x16x32_bf16(ah[s], bl, acc[f], 0, 0, 0);
    }
  }
#pragma unroll
  for (int f = 0; f < 8; ++f) {
    const int c = colq * 128 + f * 16 + lr;
    const float bb = b1[c];
#pragma unroll
    for (int q = 0; q < 4; ++q) {
      const int r = rowg * 16 + lg * 4 + q;
      const float v = fmaxf(acc[f][q] + bb, 0.f);
      const ushort h = f2bf(v);
      hh[r * HSTR + c] = h;
      hl[r * HSTR + c] = f2bf(v - bf2f(h));
    }
  }
  __syncthreads();

  // phase B: wave w: o-block (w&3)*16, rows (w>>2)*16..+15
  const int ob16 = (w & 3) * 16, rb = w >> 2;
  f32x4 acc2 = {};
#pragma unroll 4
  for (int s = 0; s < 16; ++s) {
    const size_t wo = (size_t)(ob16 + lr) * 512 + s * 32 + lg * 8;
    const bf16x8 a2h = *(const bf16x8*)&W2H[wo];
    const bf16x8 a2l = *(const bf16x8*)&W2L[wo];
    const int ko = s * 32 + lg * 8;
    const bf16x8 b2h = *(const bf16x8*)&hh[(rb * 16 + lr) * HSTR + ko];
    const bf16x8 b2l = *(const bf16x8*)&hl[(rb * 16 + lr) * HSTR + ko];
    acc2 = __builtin_amdgcn_mfma_f32_16x16x32_bf16(a2h, b2h, acc2, 0, 0, 0);
    acc2 = __builtin_amdgcn_mfma_f32_16x16x32_bf16(a2l, b2h, acc2, 0, 0, 0);
    acc2 = __builtin_amdgcn_mfma_f32_16x16x32_bf16(a2h, b2l, acc2, 0, 0, 0);
  }
  // D: batch row = rb*16 + (lane&15), o = ob16 + 4*(lane>>4)+q
  const float4 bb2 = *(const float4*)&b2[ob16 + lg * 4];
  float4 o;
  o.x = acc2[0] + bb2.x;
  o.y = acc2[1] + bb2.y;
  o.z = acc2[2] + bb2.z;
  o.w = acc2[3] + bb2.w;
  *(float4*)&out[(size_t)(row0 + rb * 16 + lr) * 64 + ob16 + lg * 4] = o;
}

}  // namespace

extern "C" void kernel_launch(void* const* d_in, const int* in_sizes, int n_in,
                              void* d_out, int out_size, void* d_ws,
                              size_t ws_size, hipStream_t stream) {
  const float* E  = (const float*)d_in[0];
  const float* Wm = (const float*)d_in[1];
  const float* W1 = (const float*)d_in[2];
  const float* b1 = (const float*)d_in[3];
  const float* W2 = (const float*)d_in[4];
  const float* b2 = (const float*)d_in[5];
  const int* eids = (const int*)d_in[6];
  const int* mids = (const int*)d_in[7];
  float* out = (float*)d_out;
  float* ws = (float*)d_ws;

  k_prep<<<dim3(752), dim3(256), 0, stream>>>(Wm, W1, W2, mids, ws);
  k_hop<0><<<dim3(256), dim3(512), 0, stream>>>(E, eids, ws);
  k_hop<1><<<dim3(256), dim3(512), 0, stream>>>(E, eids, ws);
  k_hop<2><<<dim3(256), dim3(512), 0, stream>>>(E, eids, ws);
  k_mlp<<<dim3(256), dim3(512), 0, stream>>>(b1, b2, ws, out);
}

// Round 19
// 73.101 us; speedup vs baseline: 1.0541x; 1.0541x over previous
//
#include <hip/hip_runtime.h>

namespace {

typedef short bf16x8 __attribute__((ext_vector_type(8)));
typedef float f32x4 __attribute__((ext_vector_type(4)));

constexpr int BATCH = 8192;
constexpr int NMOD  = 64;
constexpr int CAP   = 256;   // Bin(8192,1/64) max ~170 << 256 (validated r1-r18)
constexpr int CSTR  = 16;    // counter stride in ints = 64B
constexpr float WB  = 1.0f / (7.0f * 0.5f);  // 2/7

// ws layout (float offsets) — r9/r14 layout
constexpr size_t OFF_WHI = 0;        // ushort[64*128*128] Wm hi [m][o][i]
constexpr size_t OFF_WLO = 524288;   // lo
constexpr size_t OFF_XH0 = 1048576;  // ushort[8192*128] X hi (hop0/2 out)
constexpr size_t OFF_XL0 = 1572864;  // lo
constexpr size_t OFF_XH1 = 2097152;  // ushort[8192*128] X hi (hop1 out)
constexpr size_t OFF_XL1 = 2621440;  // lo
constexpr size_t OFF_W1H = 3145728;  // ushort[512*128] W1 hi [col][k]
constexpr size_t OFF_W1L = 3178496;
constexpr size_t OFF_W2H = 3211264;  // ushort[64*512]  W2 hi [o][k]
constexpr size_t OFF_W2L = 3227648;
constexpr size_t OFF_CNT = 3244032;  // 192*CSTR ints (zeroed by memset)
constexpr size_t OFF_BKT = 3247104;  // 3*64*CAP ints

__device__ __forceinline__ ushort f2bf(float x) {  // RTN-even f32->bf16 bits
  unsigned u = __builtin_bit_cast(unsigned, x);
  u += 0x7FFFu + ((u >> 16) & 1u);
  return (ushort)(u >> 16);
}
__device__ __forceinline__ float bf2f(ushort h) {
  return __builtin_bit_cast(float, ((unsigned)h) << 16);
}
__device__ __forceinline__ void cvt8(const float* v, bf16x8& hi, bf16x8& lo) {
#pragma unroll
  for (int j = 0; j < 8; ++j) {
    const float x = v[j];
    const ushort h = f2bf(x);
    hi[j] = (short)h;
    lo[j] = (short)f2bf(x - bf2f(h));
  }
}

// ---- prep (r17-proven): hi/lo conversions + atomic bucket scatter ---------
// bx 0..511: Wm; 512..543: W1; 544..559: W2; 560..655: scatter
__global__ __launch_bounds__(256) void k_prep(const float* __restrict__ Wm,
                                              const float* __restrict__ W1,
                                              const float* __restrict__ W2,
                                              const int* __restrict__ mids,
                                              float* __restrict__ ws) {
  const int bx = blockIdx.x;
  const int tid = threadIdx.x;
  if (bx < 560) {  // elementwise f32 -> bf16 hi/lo, layout preserved
    const float* src;
    ushort *dh, *dl;
    size_t i8;
    if (bx < 512) {
      src = Wm; dh = (ushort*)(ws + OFF_WHI); dl = (ushort*)(ws + OFF_WLO);
      i8 = (size_t)bx * 256 + tid;
    } else if (bx < 544) {
      src = W1; dh = (ushort*)(ws + OFF_W1H); dl = (ushort*)(ws + OFF_W1L);
      i8 = (size_t)(bx - 512) * 256 + tid;
    } else {
      src = W2; dh = (ushort*)(ws + OFF_W2H); dl = (ushort*)(ws + OFF_W2L);
      i8 = (size_t)(bx - 544) * 256 + tid;
    }
    float v[8];
    *(float4*)&v[0] = *(const float4*)&src[i8 * 8];
    *(float4*)&v[4] = *(const float4*)&src[i8 * 8 + 4];
    bf16x8 hi, lo;
    cvt8(v, hi, lo);
    *(bf16x8*)&dh[i8 * 8] = hi;
    *(bf16x8*)&dl[i8 * 8] = lo;
  } else {  // bucket scatter; padded counters
    const int idx = (bx - 560) * 256 + tid;
    if (idx < BATCH * 3) {
      const int b = idx / 3, h = idx - b * 3;
      const int m = mids[idx];
      int* cnt = (int*)(ws + OFF_CNT);
      int* bkt = (int*)(ws + OFF_BKT);
      const int pos = atomicAdd(&cnt[(h * NMOD + m) * CSTR], 1);
      bkt[(h * NMOD + m) * CAP + pos] = b;
    }
  }
}

// ---- hop (r17-proven): 512-thread blocks, 8 waves share one staged tile ---
template <int HOP>
__global__ __launch_bounds__(512, 1) void k_hop(const float* __restrict__ E,
                                                const int* __restrict__ eids,
                                                float* __restrict__ ws) {
  const int m = blockIdx.x >> 2, sl = blockIdx.x & 3;
  const int cn = ((const int*)(ws + OFF_CNT))[(HOP * NMOD + m) * CSTR];
  const int r0 = sl * 64;
  if (r0 >= cn) return;
  const int nr = min(64, cn - r0);

  __shared__ ushort wh[128 * 72];  // 18 KB
  __shared__ ushort wl[128 * 72];  // 18 KB
  __shared__ int rows[64], esrc[64], ebia[64];

  const int tid = threadIdx.x;
  const ushort* WhiG = (const ushort*)(ws + OFF_WHI) + (size_t)m * 16384;
  const ushort* WloG = (const ushort*)(ws + OFF_WLO) + (size_t)m * 16384;
  const int* bkt = (const int*)(ws + OFF_BKT) + (HOP * NMOD + m) * CAP + r0;
  const ushort* XHp = (const ushort*)(ws + (HOP == 2 ? OFF_XH1 : OFF_XH0));
  const ushort* XLp = (const ushort*)(ws + (HOP == 2 ? OFF_XL1 : OFF_XL0));
  ushort* XHn = (ushort*)(ws + (HOP == 1 ? OFF_XH1 : OFF_XH0));
  ushort* XLn = (ushort*)(ws + (HOP == 1 ? OFF_XL1 : OFF_XL0));

  if (tid < 64) {
    const int b = bkt[tid < nr ? tid : 0];
    rows[tid] = b;
    esrc[tid] = (HOP == 0) ? eids[b * 4] : b;
    ebia[tid] = eids[b * 4 + HOP + 1];
  }

  const int w = tid >> 6, l = tid & 63;
  const int lg = l >> 4, lr = l & 15;
  const int g = w & 3;            // rowgroup (16 rows)
  const int f0 = (w >> 2) * 4;    // first of 4 colfrags

  f32x4 acc[4] = {};

#pragma unroll
  for (int p = 0; p < 2; ++p) {
    __syncthreads();  // rows ready (p=0) / prev phase reads done (p=1)
    for (int e = tid; e < 128 * 8; e += 512) {
      const int c = e >> 3, s = e & 7;
      *(bf16x8*)&wh[c * 72 + s * 8] =
          *(const bf16x8*)&WhiG[(size_t)c * 128 + p * 64 + s * 8];
      *(bf16x8*)&wl[c * 72 + s * 8] =
          *(const bf16x8*)&WloG[(size_t)c * 128 + p * 64 + s * 8];
    }
    __syncthreads();

    bf16x8 ah[2], al[2];
    {
      const int row = g * 16 + lr;
#pragma unroll
      for (int s = 0; s < 2; ++s) {
        const int k0 = p * 64 + s * 32 + lg * 8;
        if (HOP == 0) {
          const float* sp = E + (size_t)esrc[row] * 128;
          float v[8];
          *(float4*)&v[0] = *(const float4*)&sp[k0];
          *(float4*)&v[4] = *(const float4*)&sp[k0 + 4];
          cvt8(v, ah[s], al[s]);
        } else {
          const size_t xo = (size_t)esrc[row] * 128 + k0;
          ah[s] = *(const bf16x8*)&XHp[xo];
          al[s] = *(const bf16x8*)&XLp[xo];
        }
      }
    }

#pragma unroll
    for (int f = 0; f < 4; ++f) {
      const int c = (f0 + f) * 16 + lr;
#pragma unroll
      for (int s = 0; s < 2; ++s) {
        const bf16x8 bh = *(const bf16x8*)&wh[c * 72 + s * 32 + lg * 8];
        const bf16x8 bl = *(const bf16x8*)&wl[c * 72 + s * 32 + lg * 8];
        acc[f] = __builtin_amdgcn_mfma_f32_16x16x32_bf16(ah[s], bh, acc[f], 0, 0, 0);
        acc[f] = __builtin_amdgcn_mfma_f32_16x16x32_bf16(al[s], bh, acc[f], 0, 0, 0);
        acc[f] = __builtin_amdgcn_mfma_f32_16x16x32_bf16(ah[s], bl, acc[f], 0, 0, 0);
      }
    }
  }

  // epilogue: C/D col=lane&15, row=4*(lane>>4)+q (validated r8/r9)
#pragma unroll
  for (int q = 0; q < 4; ++q) {
    const int row = g * 16 + lg * 4 + q;
    if (row < nr) {
      const int b = rows[row];
      const float* bp = E + (size_t)ebia[row] * 128;
      const size_t ob = (size_t)b * 128;
#pragma unroll
      for (int f = 0; f < 4; ++f) {
        const int col = (f0 + f) * 16 + lr;
        const float bias = bp[col];
        float v = fmaxf(acc[f][q] + bias, 0.f);
        if (HOP == 2) v = (1.f - WB) * bias + WB * v;
        const ushort h = f2bf(v);
        XHn[ob + col] = h;
        XLn[ob + col] = f2bf(v - bf2f(h));
      }
    }
  }
}

// ---- fused MLP (r18): 512-thread, 32-row blocks (grid 256) ----------------
constexpr int HSTR = 520;
__global__ __launch_bounds__(512, 2) void k_mlp(const float* __restrict__ b1,
                                                const float* __restrict__ b2,
                                                float* __restrict__ ws,
                                                float* __restrict__ out) {
  __shared__ ushort hh[32 * HSTR];  // 33280 B
  __shared__ ushort hl[32 * HSTR];  // 33280 B (total 66560 -> 2 blocks/CU)
  const int tid = threadIdx.x;
  const int row0 = blockIdx.x * 32;
  const ushort* XH = (const ushort*)(ws + OFF_XH0);
  const ushort* XL = (const ushort*)(ws + OFF_XL0);
  const ushort* W1H = (const ushort*)(ws + OFF_W1H);
  const ushort* W1L = (const ushort*)(ws + OFF_W1L);
  const ushort* W2H = (const ushort*)(ws + OFF_W2H);
  const ushort* W2L = (const ushort*)(ws + OFF_W2L);

  const int w = tid >> 6, l = tid & 63;
  const int lg = l >> 4, lr = l & 15;

  // phase A: wave w handles rows rowg*16..+15, cols colq*128..+127
  const int rowg = w & 1, colq = w >> 1;
  bf16x8 ah[4], al[4];
#pragma unroll
  for (int s = 0; s < 4; ++s) {
    const size_t xo = (size_t)(row0 + rowg * 16 + lr) * 128 + s * 32 + lg * 8;
    ah[s] = *(const bf16x8*)&XH[xo];
    al[s] = *(const bf16x8*)&XL[xo];
  }
  f32x4 acc[8] = {};
#pragma unroll
  for (int f = 0; f < 8; ++f) {
    const int c = colq * 128 + f * 16 + lr;
#pragma unroll
    for (int s = 0; s < 4; ++s) {
      const size_t wo = (size_t)c * 128 + s * 32 + lg * 8;
      const bf16x8 bh = *(const bf16x8*)&W1H[wo];
      const bf16x8 bl = *(const bf16x8*)&W1L[wo];
      acc[f] = __builtin_amdgcn_mfma_f32_16x16x32_bf16(ah[s], bh, acc[f], 0, 0, 0);
      acc[f] = __builtin_amdgcn_mfma_f32_16x16x32_bf16(al[s], bh, acc[f], 0, 0, 0);
      acc[f] = __builtin_amdgcn_mfma_f32_16x16x32_bf16(ah[s], bl, acc[f], 0, 0, 0);
    }
  }
#pragma unroll
  for (int f = 0; f < 8; ++f) {
    const int c = colq * 128 + f * 16 + lr;
    const float bb = b1[c];
#pragma unroll
    for (int q = 0; q < 4; ++q) {
      const int r = rowg * 16 + lg * 4 + q;
      const float v = fmaxf(acc[f][q] + bb, 0.f);
      const ushort h = f2bf(v);
      hh[r * HSTR + c] = h;
      hl[r * HSTR + c] = f2bf(v - bf2f(h));
    }
  }
  __syncthreads();

  // phase B: wave w: o-block (w&3)*16, rows (w>>2)*16..+15
  const int ob16 = (w & 3) * 16, rb = w >> 2;
  f32x4 acc2 = {};
#pragma unroll 4
  for (int s = 0; s < 16; ++s) {
    const size_t wo = (size_t)(ob16 + lr) * 512 + s * 32 + lg * 8;
    const bf16x8 a2h = *(const bf16x8*)&W2H[wo];
    const bf16x8 a2l = *(const bf16x8*)&W2L[wo];
    const int ko = s * 32 + lg * 8;
    const bf16x8 b2h = *(const bf16x8*)&hh[(rb * 16 + lr) * HSTR + ko];
    const bf16x8 b2l = *(const bf16x8*)&hl[(rb * 16 + lr) * HSTR + ko];
    acc2 = __builtin_amdgcn_mfma_f32_16x16x32_bf16(a2h, b2h, acc2, 0, 0, 0);
    acc2 = __builtin_amdgcn_mfma_f32_16x16x32_bf16(a2l, b2h, acc2, 0, 0, 0);
    acc2 = __builtin_amdgcn_mfma_f32_16x16x32_bf16(a2h, b2l, acc2, 0, 0, 0);
  }
  // D: batch row = rb*16 + (lane&15), o = ob16 + 4*(lane>>4)+q
  const float4 bb2 = *(const float4*)&b2[ob16 + lg * 4];
  float4 o;
  o.x = acc2[0] + bb2.x;
  o.y = acc2[1] + bb2.y;
  o.z = acc2[2] + bb2.z;
  o.w = acc2[3] + bb2.w;
  *(float4*)&out[(size_t)(row0 + rb * 16 + lr) * 64 + ob16 + lg * 4] = o;
}

}  // namespace

extern "C" void kernel_launch(void* const* d_in, const int* in_sizes, int n_in,
                              void* d_out, int out_size, void* d_ws,
                              size_t ws_size, hipStream_t stream) {
  const float* E  = (const float*)d_in[0];
  const float* Wm = (const float*)d_in[1];
  const float* W1 = (const float*)d_in[2];
  const float* b1 = (const float*)d_in[3];
  const float* W2 = (const float*)d_in[4];
  const float* b2 = (const float*)d_in[5];
  const int* eids = (const int*)d_in[6];
  const int* mids = (const int*)d_in[7];
  float* out = (float*)d_out;
  float* ws = (float*)d_ws;

  (void)hipMemsetAsync((char*)d_ws + OFF_CNT * sizeof(float), 0,
                       192 * CSTR * sizeof(int), stream);
  k_prep<<<dim3(656), dim3(256), 0, stream>>>(Wm, W1, W2, mids, ws);
  k_hop<0><<<dim3(256), dim3(512), 0, stream>>>(E, eids, ws);
  k_hop<1><<<dim3(256), dim3(512), 0, stream>>>(E, eids, ws);
  k_hop<2><<<dim3(256), dim3(512), 0, stream>>>(E, eids, ws);
  k_mlp<<<dim3(256), dim3(512), 0, stream>>>(b1, b2, ws, out);
}

// Round 20
// 71.845 us; speedup vs baseline: 1.0725x; 1.0175x over previous
//
#include <hip/hip_runtime.h>

namespace {

typedef short bf16x8 __attribute__((ext_vector_type(8)));
typedef float f32x4 __attribute__((ext_vector_type(4)));

constexpr int BATCH = 8192;
constexpr int NMOD  = 64;
constexpr int CAP   = 256;   // Bin(8192,1/64) max ~170 << 256 (validated r1-r19)
constexpr int CSTR  = 16;    // counter stride in ints = 64B
constexpr float WB  = 1.0f / (7.0f * 0.5f);  // 2/7

// ws layout (float offsets) — r9/r14 layout
constexpr size_t OFF_WHI = 0;        // ushort[64*128*128] Wm hi [m][o][i]
constexpr size_t OFF_WLO = 524288;   // lo
constexpr size_t OFF_XH0 = 1048576;  // ushort[8192*128] X hi (hop0/2 out)
constexpr size_t OFF_XL0 = 1572864;  // lo
constexpr size_t OFF_XH1 = 2097152;  // ushort[8192*128] X hi (hop1 out)
constexpr size_t OFF_XL1 = 2621440;  // lo
constexpr size_t OFF_W1H = 3145728;  // ushort[512*128] W1 hi [col][k]
constexpr size_t OFF_W1L = 3178496;
constexpr size_t OFF_W2H = 3211264;  // ushort[64*512]  W2 hi [o][k]
constexpr size_t OFF_W2L = 3227648;
constexpr size_t OFF_CNT = 3244032;  // 192*CSTR ints (zeroed by memset)
constexpr size_t OFF_BKT = 3247104;  // 3*64*CAP ints

__device__ __forceinline__ ushort f2bf(float x) {  // RTN-even f32->bf16 bits
  unsigned u = __builtin_bit_cast(unsigned, x);
  u += 0x7FFFu + ((u >> 16) & 1u);
  return (ushort)(u >> 16);
}
__device__ __forceinline__ float bf2f(ushort h) {
  return __builtin_bit_cast(float, ((unsigned)h) << 16);
}
__device__ __forceinline__ void cvt8(const float* v, bf16x8& hi, bf16x8& lo) {
#pragma unroll
  for (int j = 0; j < 8; ++j) {
    const float x = v[j];
    const ushort h = f2bf(x);
    hi[j] = (short)h;
    lo[j] = (short)f2bf(x - bf2f(h));
  }
}

// ---- prep (r9-proven): hi/lo conversions + atomic bucket scatter ----------
// bx 0..511: Wm; 512..543: W1; 544..559: W2; 560..655: scatter
__global__ __launch_bounds__(256) void k_prep(const float* __restrict__ Wm,
                                              const float* __restrict__ W1,
                                              const float* __restrict__ W2,
                                              const int* __restrict__ mids,
                                              float* __restrict__ ws) {
  const int bx = blockIdx.x;
  const int tid = threadIdx.x;
  if (bx < 560) {  // elementwise f32 -> bf16 hi/lo, layout preserved
    const float* src;
    ushort *dh, *dl;
    size_t i8;
    if (bx < 512) {
      src = Wm; dh = (ushort*)(ws + OFF_WHI); dl = (ushort*)(ws + OFF_WLO);
      i8 = (size_t)bx * 256 + tid;
    } else if (bx < 544) {
      src = W1; dh = (ushort*)(ws + OFF_W1H); dl = (ushort*)(ws + OFF_W1L);
      i8 = (size_t)(bx - 512) * 256 + tid;
    } else {
      src = W2; dh = (ushort*)(ws + OFF_W2H); dl = (ushort*)(ws + OFF_W2L);
      i8 = (size_t)(bx - 544) * 256 + tid;
    }
    float v[8];
    *(float4*)&v[0] = *(const float4*)&src[i8 * 8];
    *(float4*)&v[4] = *(const float4*)&src[i8 * 8 + 4];
    bf16x8 hi, lo;
    cvt8(v, hi, lo);
    *(bf16x8*)&dh[i8 * 8] = hi;
    *(bf16x8*)&dl[i8 * 8] = lo;
  } else {  // bucket scatter; padded counters
    const int idx = (bx - 560) * 256 + tid;
    if (idx < BATCH * 3) {
      const int b = idx / 3, h = idx - b * 3;
      const int m = mids[idx];
      int* cnt = (int*)(ws + OFF_CNT);
      int* bkt = (int*)(ws + OFF_BKT);
      const int pos = atomicAdd(&cnt[(h * NMOD + m) * CSTR], 1);
      bkt[(h * NMOD + m) * CAP + pos] = b;
    }
  }
}

// ---- hop (r17-proven): 512-thread blocks, 8 waves share one staged tile ---
template <int HOP>
__global__ __launch_bounds__(512, 1) void k_hop(const float* __restrict__ E,
                                                const int* __restrict__ eids,
                                                float* __restrict__ ws) {
  const int m = blockIdx.x >> 2, sl = blockIdx.x & 3;
  const int cn = ((const int*)(ws + OFF_CNT))[(HOP * NMOD + m) * CSTR];
  const int r0 = sl * 64;
  if (r0 >= cn) return;
  const int nr = min(64, cn - r0);

  __shared__ ushort wh[128 * 72];  // 18 KB
  __shared__ ushort wl[128 * 72];  // 18 KB
  __shared__ int rows[64], esrc[64], ebia[64];

  const int tid = threadIdx.x;
  const ushort* WhiG = (const ushort*)(ws + OFF_WHI) + (size_t)m * 16384;
  const ushort* WloG = (const ushort*)(ws + OFF_WLO) + (size_t)m * 16384;
  const int* bkt = (const int*)(ws + OFF_BKT) + (HOP * NMOD + m) * CAP + r0;
  const ushort* XHp = (const ushort*)(ws + (HOP == 2 ? OFF_XH1 : OFF_XH0));
  const ushort* XLp = (const ushort*)(ws + (HOP == 2 ? OFF_XL1 : OFF_XL0));
  ushort* XHn = (ushort*)(ws + (HOP == 1 ? OFF_XH1 : OFF_XH0));
  ushort* XLn = (ushort*)(ws + (HOP == 1 ? OFF_XL1 : OFF_XL0));

  if (tid < 64) {
    const int b = bkt[tid < nr ? tid : 0];
    rows[tid] = b;
    esrc[tid] = (HOP == 0) ? eids[b * 4] : b;
    ebia[tid] = eids[b * 4 + HOP + 1];
  }

  const int w = tid >> 6, l = tid & 63;
  const int lg = l >> 4, lr = l & 15;
  const int g = w & 3;            // rowgroup (16 rows)
  const int f0 = (w >> 2) * 4;    // first of 4 colfrags

  f32x4 acc[4] = {};

#pragma unroll
  for (int p = 0; p < 2; ++p) {
    __syncthreads();  // rows ready (p=0) / prev phase reads done (p=1)
    for (int e = tid; e < 128 * 8; e += 512) {
      const int c = e >> 3, s = e & 7;
      *(bf16x8*)&wh[c * 72 + s * 8] =
          *(const bf16x8*)&WhiG[(size_t)c * 128 + p * 64 + s * 8];
      *(bf16x8*)&wl[c * 72 + s * 8] =
          *(const bf16x8*)&WloG[(size_t)c * 128 + p * 64 + s * 8];
    }
    __syncthreads();

    bf16x8 ah[2], al[2];
    {
      const int row = g * 16 + lr;
#pragma unroll
      for (int s = 0; s < 2; ++s) {
        const int k0 = p * 64 + s * 32 + lg * 8;
        if (HOP == 0) {
          const float* sp = E + (size_t)esrc[row] * 128;
          float v[8];
          *(float4*)&v[0] = *(const float4*)&sp[k0];
          *(float4*)&v[4] = *(const float4*)&sp[k0 + 4];
          cvt8(v, ah[s], al[s]);
        } else {
          const size_t xo = (size_t)esrc[row] * 128 + k0;
          ah[s] = *(const bf16x8*)&XHp[xo];
          al[s] = *(const bf16x8*)&XLp[xo];
        }
      }
    }

#pragma unroll
    for (int f = 0; f < 4; ++f) {
      const int c = (f0 + f) * 16 + lr;
#pragma unroll
      for (int s = 0; s < 2; ++s) {
        const bf16x8 bh = *(const bf16x8*)&wh[c * 72 + s * 32 + lg * 8];
        const bf16x8 bl = *(const bf16x8*)&wl[c * 72 + s * 32 + lg * 8];
        acc[f] = __builtin_amdgcn_mfma_f32_16x16x32_bf16(ah[s], bh, acc[f], 0, 0, 0);
        acc[f] = __builtin_amdgcn_mfma_f32_16x16x32_bf16(al[s], bh, acc[f], 0, 0, 0);
        acc[f] = __builtin_amdgcn_mfma_f32_16x16x32_bf16(ah[s], bl, acc[f], 0, 0, 0);
      }
    }
  }

  // epilogue: C/D col=lane&15, row=4*(lane>>4)+q (validated r8/r9)
#pragma unroll
  for (int q = 0; q < 4; ++q) {
    const int row = g * 16 + lg * 4 + q;
    if (row < nr) {
      const int b = rows[row];
      const float* bp = E + (size_t)ebia[row] * 128;
      const size_t ob = (size_t)b * 128;
#pragma unroll
      for (int f = 0; f < 4; ++f) {
        const int col = (f0 + f) * 16 + lr;
        const float bias = bp[col];
        float v = fmaxf(acc[f][q] + bias, 0.f);
        if (HOP == 2) v = (1.f - WB) * bias + WB * v;
        const ushort h = f2bf(v);
        XHn[ob + col] = h;
        XLn[ob + col] = f2bf(v - bf2f(h));
      }
    }
  }
}

// ---- fused MLP (r14/r17-proven): W1 LDS-staged in 8 chunks of 64 cols -----
constexpr int HSTR = 520;
constexpr int WSTR = 136;  // staged W1 col stride (ushorts), 16B-aligned
__global__ __launch_bounds__(256, 2) void k_mlp(const float* __restrict__ b1,
                                                const float* __restrict__ b2,
                                                float* __restrict__ ws,
                                                float* __restrict__ out) {
  __shared__ ushort w1h[64 * WSTR];  // 17408 B
  __shared__ ushort w1l[64 * WSTR];  // 17408 B
  __shared__ ushort hh[16 * HSTR];   // 16640 B
  __shared__ ushort hl[16 * HSTR];   // 16640 B  (total 68096 B -> 2/CU)
  const int tid = threadIdx.x;
  const int row0 = blockIdx.x * 16;
  const ushort* XH = (const ushort*)(ws + OFF_XH0);
  const ushort* XL = (const ushort*)(ws + OFF_XL0);
  const ushort* W1H = (const ushort*)(ws + OFF_W1H);
  const ushort* W1L = (const ushort*)(ws + OFF_W1L);
  const ushort* W2H = (const ushort*)(ws + OFF_W2H);
  const ushort* W2L = (const ushort*)(ws + OFF_W2L);

  const int w = tid >> 6, l = tid & 63;
  const int lg = l >> 4, lr = l & 15;

  // A-frags for the block's 16 rows (held in regs across all chunks)
  bf16x8 ah[4], al[4];
#pragma unroll
  for (int s = 0; s < 4; ++s) {
    const size_t xo = (size_t)(row0 + lr) * 128 + s * 32 + lg * 8;
    ah[s] = *(const bf16x8*)&XH[xo];
    al[s] = *(const bf16x8*)&XL[xo];
  }

  // phase A: 8 chunks of 64 cols
  for (int ch = 0; ch < 8; ++ch) {
    __syncthreads();  // prev chunk's LDS reads done
    for (int e = tid; e < 64 * 16; e += 256) {
      const int c = e >> 4, s8 = e & 15;
      const size_t go = (size_t)(ch * 64 + c) * 128 + s8 * 8;
      *(bf16x8*)&w1h[c * WSTR + s8 * 8] = *(const bf16x8*)&W1H[go];
      *(bf16x8*)&w1l[c * WSTR + s8 * 8] = *(const bf16x8*)&W1L[go];
    }
    __syncthreads();

    const int cl = w * 16 + lr;  // col within chunk owned by this lane
    f32x4 a = {};
#pragma unroll
    for (int s = 0; s < 4; ++s) {
      const bf16x8 bh = *(const bf16x8*)&w1h[cl * WSTR + s * 32 + lg * 8];
      const bf16x8 bl = *(const bf16x8*)&w1l[cl * WSTR + s * 32 + lg * 8];
      a = __builtin_amdgcn_mfma_f32_16x16x32_bf16(ah[s], bh, a, 0, 0, 0);
      a = __builtin_amdgcn_mfma_f32_16x16x32_bf16(al[s], bh, a, 0, 0, 0);
      a = __builtin_amdgcn_mfma_f32_16x16x32_bf16(ah[s], bl, a, 0, 0, 0);
    }
    const int c = ch * 64 + w * 16 + lr;
    const float bb = b1[c];
#pragma unroll
    for (int q = 0; q < 4; ++q) {
      const int r = lg * 4 + q;
      const float v = fmaxf(a[q] + bb, 0.f);
      const ushort h = f2bf(v);
      hh[r * HSTR + c] = h;
      hl[r * HSTR + c] = f2bf(v - bf2f(h));
    }
  }
  __syncthreads();

  // phase B: A = W2 [o][k], B = H^T from LDS; wave w owns o 16w..16w+15
  f32x4 acc2 = {};
#pragma unroll 4
  for (int s = 0; s < 16; ++s) {
    const size_t wo = (size_t)(w * 16 + lr) * 512 + s * 32 + lg * 8;
    const bf16x8 a2h = *(const bf16x8*)&W2H[wo];
    const bf16x8 a2l = *(const bf16x8*)&W2L[wo];
    const int ko = s * 32 + lg * 8;
    const bf16x8 b2h = *(const bf16x8*)&hh[lr * HSTR + ko];
    const bf16x8 b2l = *(const bf16x8*)&hl[lr * HSTR + ko];
    acc2 = __builtin_amdgcn_mfma_f32_16x16x32_bf16(a2h, b2h, acc2, 0, 0, 0);
    acc2 = __builtin_amdgcn_mfma_f32_16x16x32_bf16(a2l, b2h, acc2, 0, 0, 0);
    acc2 = __builtin_amdgcn_mfma_f32_16x16x32_bf16(a2h, b2l, acc2, 0, 0, 0);
  }
  const float4 bb2 = *(const float4*)&b2[w * 16 + lg * 4];
  float4 o;
  o.x = acc2[0] + bb2.x;
  o.y = acc2[1] + bb2.y;
  o.z = acc2[2] + bb2.z;
  o.w = acc2[3] + bb2.w;
  *(float4*)&out[(size_t)(row0 + lr) * 64 + w * 16 + lg * 4] = o;
}

}  // namespace

extern "C" void kernel_launch(void* const* d_in, const int* in_sizes, int n_in,
                              void* d_out, int out_size, void* d_ws,
                              size_t ws_size, hipStream_t stream) {
  const float* E  = (const float*)d_in[0];
  const float* Wm = (const float*)d_in[1];
  const float* W1 = (const float*)d_in[2];
  const float* b1 = (const float*)d_in[3];
  const float* W2 = (const float*)d_in[4];
  const float* b2 = (const float*)d_in[5];
  const int* eids = (const int*)d_in[6];
  const int* mids = (const int*)d_in[7];
  float* out = (float*)d_out;
  float* ws = (float*)d_ws;

  (void)hipMemsetAsync((char*)d_ws + OFF_CNT * sizeof(float), 0,
                       192 * CSTR * sizeof(int), stream);
  k_prep<<<dim3(656), dim3(256), 0, stream>>>(Wm, W1, W2, mids, ws);
  k_hop<0><<<dim3(256), dim3(512), 0, stream>>>(E, eids, ws);
  k_hop<1><<<dim3(256), dim3(512), 0, stream>>>(E, eids, ws);
  k_hop<2><<<dim3(256), dim3(512), 0, stream>>>(E, eids, ws);
  k_mlp<<<dim3(512), dim3(256), 0, stream>>>(b1, b2, ws, out);
}